// Round 8
// baseline (100.954 us; speedup 1.0000x reference)
//
#include <hip/hip_runtime.h>

// Problem constants (match reference)
#define NV 300000
#define FDIM 64
#define KN 9

typedef float f32x4 __attribute__((ext_vector_type(4)));

// ---------------- bf16 helpers ----------------
__device__ __forceinline__ unsigned int bf16_rne(float x) {
    unsigned int u = __float_as_uint(x);
    return u + 0x7FFFu + ((u >> 16) & 1u);   // round-to-nearest-even in high 16
}
__device__ __forceinline__ unsigned int bf16pair(float a, float b) {
    return (bf16_rne(a) >> 16) | (bf16_rne(b) & 0xFFFF0000u);
}
__device__ __forceinline__ f32x4 unpack_bf16x4(uint2 g) {
    f32x4 r;
    r.x = __uint_as_float(g.x << 16);
    r.y = __uint_as_float(g.x & 0xFFFF0000u);
    r.z = __uint_as_float(g.y << 16);
    r.w = __uint_as_float(g.y & 0xFFFF0000u);
    return r;
}

// ---------------- pre-pass: hidden_state f32 -> bf16 table ----------------
__global__ __launch_bounds__(256) void compress_kernel(
    const float* __restrict__ hs, uint2* __restrict__ out)
{
    const int i = blockIdx.x * 256 + threadIdx.x;   // group of 4 floats
    const f32x4 v = ((const f32x4*)hs)[i];
    uint2 p;
    p.x = bf16pair(v.x, v.y);
    p.y = bf16pair(v.z, v.w);
    out[i] = p;
}

// ---------------- cross-lane helpers ----------------
// broadcast lane ((lane&48)|K) to its 16-lane group: new_lane=(lane&0x10)|K
template <int K>
__device__ __forceinline__ int bcast16(int v) {
    return __builtin_amdgcn_ds_swizzle(v, (K << 5) | 0x10);
}
template <int K>
__device__ __forceinline__ float bcast16f(float v) {
    return __int_as_float(bcast16<K>(__float_as_int(v)));
}
// xor-butterfly within 16-lane group (bit4 preserved since X<16)
template <int X>
__device__ __forceinline__ float swz_xor(float v) {
    return __int_as_float(__builtin_amdgcn_ds_swizzle(__float_as_int(v), (X << 10) | 0x1F));
}

template <typename F, int... Ks>
__device__ __forceinline__ void for9_impl(F&& f, std::integer_sequence<int, Ks...>) {
    (f(std::integral_constant<int, Ks>{}), ...);
}
template <typename F>
__device__ __forceinline__ void for9(F&& f) {
    for9_impl(f, std::make_integer_sequence<int, KN>{});
}

// ---------------- main kernel ----------------
// 16-lane group per 2 vertices (A,B); lane sl owns 4 features AND (for sl<9)
// neighbor slot k=sl. Distance reduce via LDS transpose: lane writes 9
// partials, reads back its k-column, tree-sums in registers.
__global__ __launch_bounds__(256) void aflow_kernel(
    const float* __restrict__ lattice_values,  // (N, F)
    const uint2* __restrict__ hidden_b16,      // (N, 16) packed bf16 rows
    const float* __restrict__ bias,            // (F,)
    const float* __restrict__ alpha_p,         // scalar
    const float* __restrict__ beta_p,          // scalar
    const int*   __restrict__ neighbor_idx,    // (N, K)
    float* __restrict__ out_aflow,             // (N, F)
    float* __restrict__ out_weights,           // (N, K)
    float* __restrict__ out_idx)               // (N, K) as float values
{
    __shared__ float red[2][16][16][16];       // [set][group][k][sl] 32 KiB

    const int g  = threadIdx.x >> 4;           // 16-lane group id (0..15)
    const int sl = threadIdx.x & 15;           // sub-lane

    const int nA = blockIdx.x * 32 + g * 2;    // vertex A
    const int nB = nA + 1;                     // vertex B

    const float alpha = *alpha_p;
    const float beta  = *beta_p;
    const float ab    = alpha * beta;

    const f32x4* __restrict__ lv4 = (const f32x4*)lattice_values;
    const f32x4 bias4 = *(const f32x4*)&bias[sl * 4];

    // streamed (read-once) inputs
    const f32x4 lvA = __builtin_nontemporal_load(&lv4[nA * 16 + sl]);
    const f32x4 lvB = __builtin_nontemporal_load(&lv4[nB * 16 + sl]);
    int idxrA = -1, idxrB = -1;
    if (sl < KN) {
        idxrA = __builtin_nontemporal_load(&neighbor_idx[nA * KN + sl]);
        idxrB = __builtin_nontemporal_load(&neighbor_idx[nB * KN + sl]);
    }

    auto process = [&](int set, int n, int idxr, f32x4 lv) {
        // 1) broadcast indices, gather packed bf16 rows
        int ik[KN];
        for9([&](auto kc) {
            constexpr int k = kc.value;
            ik[k] = bcast16<k>(idxr);
        });
        uint2 gk[KN];
        #pragma unroll
        for (int k = 0; k < KN; ++k) {
            const int ic = max(ik[k], 0);
            gk[k] = hidden_b16[ic * 16 + sl];   // 128B row per group
        }

        // 2) unpack once, partial squared distances (4 features/lane)
        f32x4 h[KN];
        float p[KN];
        #pragma unroll
        for (int k = 0; k < KN; ++k) {
            h[k] = unpack_bf16x4(gk[k]);
            const f32x4 d = h[k] - lv;
            float s = d.x * d.x;
            s = fmaf(d.y, d.y, s);
            s = fmaf(d.z, d.z, s);
            s = fmaf(d.w, d.w, s);
            p[k] = s;
        }

        // 3) LDS transpose: lane sl writes p[k] to red[set][g][k][sl]
        #pragma unroll
        for (int k = 0; k < KN; ++k) red[set][g][k][sl] = p[k];

        // 4) lane sl reads k-row sl (16 contiguous floats) and tree-sums.
        //    Rows 9..15 are garbage; those lanes are masked below.
        const f32x4* rbase = (const f32x4*)&red[set][g][sl][0];
        const f32x4 q0 = rbase[0], q1 = rbase[1], q2 = rbase[2], q3 = rbase[3];
        const f32x4 qs = (q0 + q1) + (q2 + q3);
        const float sum = (qs.x + qs.y) + (qs.z + qs.w);

        // 5) distance lives in lane k ( = sl )
        const bool valid = (idxr >= 0);         // false for sl>=9 (idxr=-1)
        const float dist = valid ? __builtin_amdgcn_sqrtf(sum) : 0.0f;

        // 6) per-vertex sum of distances (16-lane butterfly)
        float t = dist;
        t += swz_xor<1>(t);
        t += swz_xor<2>(t);
        t += swz_xor<4>(t);
        t += swz_xor<8>(t);
        const float inv = __builtin_amdgcn_rcpf(t);

        // 7) weight in lane k
        float w = fmaf(-beta, fminf(dist * inv, alpha), ab);
        w = valid ? w : 0.0f;

        // 8) small outputs straight from lane k
        if (sl < KN) {
            __builtin_nontemporal_store(w, &out_weights[n * KN + sl]);
            __builtin_nontemporal_store((float)idxr, &out_idx[n * KN + sl]);
        }

        // 9) broadcast weights, aggregate
        f32x4 acc = bias4;
        for9([&](auto kc) {
            constexpr int k = kc.value;
            const float wk = bcast16f<k>(w);
            acc.x = fmaf(h[k].x, wk, acc.x);
            acc.y = fmaf(h[k].y, wk, acc.y);
            acc.z = fmaf(h[k].z, wk, acc.z);
            acc.w = fmaf(h[k].w, wk, acc.w);
        });
        __builtin_nontemporal_store(acc, &((f32x4*)out_aflow)[n * 16 + sl]);
    };

    process(0, nA, idxrA, lvA);
    process(1, nB, idxrB, lvB);
}

extern "C" void kernel_launch(void* const* d_in, const int* in_sizes, int n_in,
                              void* d_out, int out_size, void* d_ws, size_t ws_size,
                              hipStream_t stream) {
    const float* lattice_values = (const float*)d_in[0];
    const float* hidden_state   = (const float*)d_in[1];
    const float* bias           = (const float*)d_in[2];
    const float* alpha          = (const float*)d_in[3];
    const float* beta           = (const float*)d_in[4];
    const int*   neighbor_idx   = (const int*)d_in[5];

    float* out = (float*)d_out;
    float* out_aflow   = out;                           // N*F
    float* out_weights = out + (size_t)NV * FDIM;       // N*K
    float* out_idx     = out_weights + (size_t)NV * KN; // N*K

    uint2* tbl = (uint2*)d_ws;                          // 38.4 MB bf16 table
    compress_kernel<<<(NV * FDIM / 4) / 256, 256, 0, stream>>>(hidden_state, tbl);

    const int blocks = NV / 32;  // 32 vertices per 256-thread block
    aflow_kernel<<<blocks, 256, 0, stream>>>(
        lattice_values, tbl, bias, alpha, beta, neighbor_idx,
        out_aflow, out_weights, out_idx);
}

// Round 9
// 100.360 us; speedup vs baseline: 1.0059x; 1.0059x over previous
//
#include <hip/hip_runtime.h>

// Problem constants (match reference)
#define NV 300000
#define FDIM 64
#define KN 9

typedef float f32x4 __attribute__((ext_vector_type(4)));
typedef unsigned int u32x2 __attribute__((ext_vector_type(2)));

// ---------------- bf16 helpers ----------------
__device__ __forceinline__ unsigned int bf16_rne(float x) {
    unsigned int u = __float_as_uint(x);
    return u + 0x7FFFu + ((u >> 16) & 1u);   // round-to-nearest-even in high 16
}
__device__ __forceinline__ unsigned int bf16pair(float a, float b) {
    return (bf16_rne(a) >> 16) | (bf16_rne(b) & 0xFFFF0000u);
}
__device__ __forceinline__ f32x4 unpack_bf16x4(uint2 g) {
    f32x4 r;
    r.x = __uint_as_float(g.x << 16);
    r.y = __uint_as_float(g.x & 0xFFFF0000u);
    r.z = __uint_as_float(g.y << 16);
    r.w = __uint_as_float(g.y & 0xFFFF0000u);
    return r;
}

// ---------------- pre-pass: hidden_state f32 -> bf16 table ----------------
// Streaming: nontemporal both ways (table is 38.4MB > per-XCD L2; caching it
// here buys nothing for the gather kernel and evicts nothing useful).
__global__ __launch_bounds__(256) void compress_kernel(
    const float* __restrict__ hs, u32x2* __restrict__ out)
{
    const int i = blockIdx.x * 256 + threadIdx.x;   // group of 4 floats
    const f32x4 v = __builtin_nontemporal_load(&((const f32x4*)hs)[i]);
    u32x2 p;
    p.x = bf16pair(v.x, v.y);
    p.y = bf16pair(v.z, v.w);
    __builtin_nontemporal_store(p, &out[i]);
}

// ---------------- main kernel ----------------
__device__ __forceinline__ float row16_reduce_add(float x) {
    int t;
    t = __builtin_amdgcn_update_dpp(0, __float_as_int(x), 0xB1, 0xF, 0xF, true);  // quad_perm xor1
    x += __int_as_float(t);
    t = __builtin_amdgcn_update_dpp(0, __float_as_int(x), 0x4E, 0xF, 0xF, true);  // quad_perm xor2
    x += __int_as_float(t);
    t = __builtin_amdgcn_update_dpp(0, __float_as_int(x), 0x141, 0xF, 0xF, true); // row_half_mirror
    x += __int_as_float(t);
    t = __builtin_amdgcn_update_dpp(0, __float_as_int(x), 0x140, 0xF, 0xF, true); // row_mirror
    x += __int_as_float(t);
    return x;
}

template <int K>
__device__ __forceinline__ int bcast16(int v) {
    return __builtin_amdgcn_ds_swizzle(v, (K << 5) | 0x10);
}

template <typename F, int... Ks>
__device__ __forceinline__ void for9_impl(F&& f, std::integer_sequence<int, Ks...>) {
    (f(std::integral_constant<int, Ks>{}), ...);
}
template <typename F>
__device__ __forceinline__ void for9(F&& f) {
    for9_impl(f, std::make_integer_sequence<int, KN>{});
}

// 16-lane sub-group per vertex, lane = 4 features. Two vertices (A,B) per
// group for MLP: 8 vertices/wave, 32 per 256-thread block.
__global__ __launch_bounds__(256) void aflow_kernel(
    const float* __restrict__ lattice_values,  // (N, F)
    const uint2* __restrict__ hidden_b16,      // (N, 16) packed bf16 rows
    const float* __restrict__ bias,            // (F,)
    const float* __restrict__ alpha_p,         // scalar
    const float* __restrict__ beta_p,          // scalar
    const int*   __restrict__ neighbor_idx,    // (N, K)
    float* __restrict__ out_aflow,             // (N, F)
    float* __restrict__ out_weights,           // (N, K)
    float* __restrict__ out_idx)               // (N, K) as float values
{
    const int lane = threadIdx.x & 63;
    const int wave = threadIdx.x >> 6;
    const int sub  = lane >> 4;   // 16-lane group within wave
    const int sl   = lane & 15;   // sub-lane: feature group (4 floats)

    const int nA = blockIdx.x * 32 + wave * 8 + sub;  // vertex A
    const int nB = nA + 4;                            // vertex B

    const float alpha = *alpha_p;
    const float beta  = *beta_p;
    const float ab    = alpha * beta;

    const f32x4* __restrict__ lv4 = (const f32x4*)lattice_values;

    // --- streamed loads (read-once): nontemporal ---
    const f32x4 lvA = __builtin_nontemporal_load(&lv4[nA * 16 + sl]);
    const f32x4 lvB = __builtin_nontemporal_load(&lv4[nB * 16 + sl]);
    int idxrA = -1, idxrB = -1;
    if (sl < KN) {
        idxrA = __builtin_nontemporal_load(&neighbor_idx[nA * KN + sl]);
        idxrB = __builtin_nontemporal_load(&neighbor_idx[nB * KN + sl]);
    }

    // --- broadcast the 9 indices to all 16 lanes ---
    int iA[KN], iB[KN];
    for9([&](auto kc) {
        constexpr int k = kc.value;
        iA[k] = bcast16<k>(idxrA);
        iB[k] = bcast16<k>(idxrB);
    });
    int vA = 0, vB = 0;
    #pragma unroll
    for (int k = 0; k < KN; ++k) {
        vA |= (iA[k] >= 0) ? (1 << k) : 0;
        vB |= (iB[k] >= 0) ? (1 << k) : 0;
    }

    // --- issue all 18 gathers (128B bf16 rows) ---
    uint2 gA[KN], gB[KN];
    #pragma unroll
    for (int k = 0; k < KN; ++k) {
        const int ic = iA[k] >= 0 ? iA[k] : 0;
        gA[k] = hidden_b16[ic * 16 + sl];
    }
    #pragma unroll
    for (int k = 0; k < KN; ++k) {
        const int ic = iB[k] >= 0 ? iB[k] : 0;
        gB[k] = hidden_b16[ic * 16 + sl];
    }

    // --- vertex A ---
    float dA[KN];
    #pragma unroll
    for (int k = 0; k < KN; ++k) {
        const f32x4 h = unpack_bf16x4(gA[k]);
        const f32x4 d = h - lvA;
        float s = d.x * d.x;
        s = fmaf(d.y, d.y, s);
        s = fmaf(d.z, d.z, s);
        s = fmaf(d.w, d.w, s);
        s = row16_reduce_add(s);
        dA[k] = ((vA >> k) & 1) ? sqrtf(s) : 0.0f;
    }
    float sumA = 0.0f;
    #pragma unroll
    for (int k = 0; k < KN; ++k) sumA += dA[k];
    const float invA = __builtin_amdgcn_rcpf(sumA);

    f32x4 accA = *(const f32x4*)&bias[sl * 4];
    float woA = 0.0f;
    #pragma unroll
    for (int k = 0; k < KN; ++k) {
        const float dn = dA[k] * invA;
        float w = fmaf(-beta, fminf(dn, alpha), ab);   // (alpha - min(dn,alpha))*beta
        w = ((vA >> k) & 1) ? w : 0.0f;
        const f32x4 h = unpack_bf16x4(gA[k]);
        accA.x = fmaf(h.x, w, accA.x);
        accA.y = fmaf(h.y, w, accA.y);
        accA.z = fmaf(h.z, w, accA.z);
        accA.w = fmaf(h.w, w, accA.w);
        if (sl == k) woA = w;
    }
    __builtin_nontemporal_store(accA, &((f32x4*)out_aflow)[nA * 16 + sl]);

    // --- vertex B ---
    float dB[KN];
    #pragma unroll
    for (int k = 0; k < KN; ++k) {
        const f32x4 h = unpack_bf16x4(gB[k]);
        const f32x4 d = h - lvB;
        float s = d.x * d.x;
        s = fmaf(d.y, d.y, s);
        s = fmaf(d.z, d.z, s);
        s = fmaf(d.w, d.w, s);
        s = row16_reduce_add(s);
        dB[k] = ((vB >> k) & 1) ? sqrtf(s) : 0.0f;
    }
    float sumB = 0.0f;
    #pragma unroll
    for (int k = 0; k < KN; ++k) sumB += dB[k];
    const float invB = __builtin_amdgcn_rcpf(sumB);

    f32x4 accB = *(const f32x4*)&bias[sl * 4];
    float woB = 0.0f;
    #pragma unroll
    for (int k = 0; k < KN; ++k) {
        const float dn = dB[k] * invB;
        float w = fmaf(-beta, fminf(dn, alpha), ab);
        w = ((vB >> k) & 1) ? w : 0.0f;
        const f32x4 h = unpack_bf16x4(gB[k]);
        accB.x = fmaf(h.x, w, accB.x);
        accB.y = fmaf(h.y, w, accB.y);
        accB.z = fmaf(h.z, w, accB.z);
        accB.w = fmaf(h.w, w, accB.w);
        if (sl == k) woB = w;
    }
    __builtin_nontemporal_store(accB, &((f32x4*)out_aflow)[nB * 16 + sl]);

    // --- small outputs ---
    if (sl < KN) {
        __builtin_nontemporal_store(woA, &out_weights[nA * KN + sl]);
        __builtin_nontemporal_store(woB, &out_weights[nB * KN + sl]);
        __builtin_nontemporal_store((float)idxrA, &out_idx[nA * KN + sl]);
        __builtin_nontemporal_store((float)idxrB, &out_idx[nB * KN + sl]);
    }
}

extern "C" void kernel_launch(void* const* d_in, const int* in_sizes, int n_in,
                              void* d_out, int out_size, void* d_ws, size_t ws_size,
                              hipStream_t stream) {
    const float* lattice_values = (const float*)d_in[0];
    const float* hidden_state   = (const float*)d_in[1];
    const float* bias           = (const float*)d_in[2];
    const float* alpha          = (const float*)d_in[3];
    const float* beta           = (const float*)d_in[4];
    const int*   neighbor_idx   = (const int*)d_in[5];

    float* out = (float*)d_out;
    float* out_aflow   = out;                           // N*F
    float* out_weights = out + (size_t)NV * FDIM;       // N*K
    float* out_idx     = out_weights + (size_t)NV * KN; // N*K

    u32x2* tbl = (u32x2*)d_ws;                          // 38.4 MB bf16 table
    compress_kernel<<<(NV * FDIM / 4) / 256, 256, 0, stream>>>(hidden_state, tbl);

    const int blocks = NV / 32;  // 32 vertices per 256-thread block
    aflow_kernel<<<blocks, 256, 0, stream>>>(
        lattice_values, (const uint2*)tbl, bias, alpha, beta, neighbor_idx,
        out_aflow, out_weights, out_idx);
}

// Round 10
// 95.391 us; speedup vs baseline: 1.0583x; 1.0521x over previous
//
#include <hip/hip_runtime.h>

// Problem constants (match reference)
#define NV 300000
#define FDIM 64
#define KN 9

typedef float f32x4 __attribute__((ext_vector_type(4)));

// ---------------- bf16 helpers ----------------
__device__ __forceinline__ unsigned int bf16_rne(float x) {
    unsigned int u = __float_as_uint(x);
    return u + 0x7FFFu + ((u >> 16) & 1u);   // round-to-nearest-even in high 16
}
__device__ __forceinline__ unsigned int bf16pair(float a, float b) {
    return (bf16_rne(a) >> 16) | (bf16_rne(b) & 0xFFFF0000u);
}
__device__ __forceinline__ f32x4 unpack_bf16x4(uint2 g) {
    f32x4 r;
    r.x = __uint_as_float(g.x << 16);
    r.y = __uint_as_float(g.x & 0xFFFF0000u);
    r.z = __uint_as_float(g.y << 16);
    r.w = __uint_as_float(g.y & 0xFFFF0000u);
    return r;
}

// ---------------- pre-pass: hidden_state f32 -> bf16 table ----------------
// Plain cached loads/stores: measured faster than nontemporal (R7 vs R9),
// and leaves part of the table resident in L2 for the gather kernel.
__global__ __launch_bounds__(256) void compress_kernel(
    const float* __restrict__ hs, uint2* __restrict__ out)
{
    const int i = blockIdx.x * 256 + threadIdx.x;   // group of 4 floats
    const f32x4 v = ((const f32x4*)hs)[i];
    uint2 p;
    p.x = bf16pair(v.x, v.y);
    p.y = bf16pair(v.z, v.w);
    out[i] = p;
}

// ---------------- main kernel ----------------
__device__ __forceinline__ float row16_reduce_add(float x) {
    int t;
    t = __builtin_amdgcn_update_dpp(0, __float_as_int(x), 0xB1, 0xF, 0xF, true);  // quad_perm xor1
    x += __int_as_float(t);
    t = __builtin_amdgcn_update_dpp(0, __float_as_int(x), 0x4E, 0xF, 0xF, true);  // quad_perm xor2
    x += __int_as_float(t);
    t = __builtin_amdgcn_update_dpp(0, __float_as_int(x), 0x141, 0xF, 0xF, true); // row_half_mirror
    x += __int_as_float(t);
    t = __builtin_amdgcn_update_dpp(0, __float_as_int(x), 0x140, 0xF, 0xF, true); // row_mirror
    x += __int_as_float(t);
    return x;
}

template <int K>
__device__ __forceinline__ int bcast16(int v) {
    return __builtin_amdgcn_ds_swizzle(v, (K << 5) | 0x10);
}

template <typename F, int... Ks>
__device__ __forceinline__ void for9_impl(F&& f, std::integer_sequence<int, Ks...>) {
    (f(std::integral_constant<int, Ks>{}), ...);
}
template <typename F>
__device__ __forceinline__ void for9(F&& f) {
    for9_impl(f, std::make_integer_sequence<int, KN>{});
}

// 16-lane sub-group per vertex, lane = 4 features. Two vertices (A,B) per
// group for MLP: 8 vertices/wave, 32 per 256-thread block.
__global__ __launch_bounds__(256) void aflow_kernel(
    const float* __restrict__ lattice_values,  // (N, F)
    const uint2* __restrict__ hidden_b16,      // (N, 16) packed bf16 rows
    const float* __restrict__ bias,            // (F,)
    const float* __restrict__ alpha_p,         // scalar
    const float* __restrict__ beta_p,          // scalar
    const int*   __restrict__ neighbor_idx,    // (N, K)
    float* __restrict__ out_aflow,             // (N, F)
    float* __restrict__ out_weights,           // (N, K)
    float* __restrict__ out_idx)               // (N, K) as float values
{
    const int lane = threadIdx.x & 63;
    const int wave = threadIdx.x >> 6;
    const int sub  = lane >> 4;   // 16-lane group within wave
    const int sl   = lane & 15;   // sub-lane: feature group (4 floats)

    const int nA = blockIdx.x * 32 + wave * 8 + sub;  // vertex A
    const int nB = nA + 4;                            // vertex B

    const float alpha = *alpha_p;
    const float beta  = *beta_p;
    const float ab    = alpha * beta;

    const f32x4* __restrict__ lv4 = (const f32x4*)lattice_values;

    // --- streamed loads (read-once): nontemporal ---
    const f32x4 lvA = __builtin_nontemporal_load(&lv4[nA * 16 + sl]);
    const f32x4 lvB = __builtin_nontemporal_load(&lv4[nB * 16 + sl]);
    int idxrA = -1, idxrB = -1;
    if (sl < KN) {
        idxrA = __builtin_nontemporal_load(&neighbor_idx[nA * KN + sl]);
        idxrB = __builtin_nontemporal_load(&neighbor_idx[nB * KN + sl]);
    }

    // --- broadcast the 9 indices to all 16 lanes ---
    int iA[KN], iB[KN];
    for9([&](auto kc) {
        constexpr int k = kc.value;
        iA[k] = bcast16<k>(idxrA);
        iB[k] = bcast16<k>(idxrB);
    });
    int vA = 0, vB = 0;
    #pragma unroll
    for (int k = 0; k < KN; ++k) {
        vA |= (iA[k] >= 0) ? (1 << k) : 0;
        vB |= (iB[k] >= 0) ? (1 << k) : 0;
    }

    // --- issue all 18 gathers (128B bf16 rows) ---
    uint2 gA[KN], gB[KN];
    #pragma unroll
    for (int k = 0; k < KN; ++k) {
        const int ic = iA[k] >= 0 ? iA[k] : 0;
        gA[k] = hidden_b16[ic * 16 + sl];
    }
    #pragma unroll
    for (int k = 0; k < KN; ++k) {
        const int ic = iB[k] >= 0 ? iB[k] : 0;
        gB[k] = hidden_b16[ic * 16 + sl];
    }

    // --- vertex A ---
    float dA[KN];
    #pragma unroll
    for (int k = 0; k < KN; ++k) {
        const f32x4 h = unpack_bf16x4(gA[k]);
        const f32x4 d = h - lvA;
        float s = d.x * d.x;
        s = fmaf(d.y, d.y, s);
        s = fmaf(d.z, d.z, s);
        s = fmaf(d.w, d.w, s);
        s = row16_reduce_add(s);
        dA[k] = ((vA >> k) & 1) ? sqrtf(s) : 0.0f;
    }
    float sumA = 0.0f;
    #pragma unroll
    for (int k = 0; k < KN; ++k) sumA += dA[k];
    const float invA = __builtin_amdgcn_rcpf(sumA);

    f32x4 accA = *(const f32x4*)&bias[sl * 4];
    float woA = 0.0f;
    #pragma unroll
    for (int k = 0; k < KN; ++k) {
        const float dn = dA[k] * invA;
        float w = fmaf(-beta, fminf(dn, alpha), ab);   // (alpha - min(dn,alpha))*beta
        w = ((vA >> k) & 1) ? w : 0.0f;
        const f32x4 h = unpack_bf16x4(gA[k]);
        accA.x = fmaf(h.x, w, accA.x);
        accA.y = fmaf(h.y, w, accA.y);
        accA.z = fmaf(h.z, w, accA.z);
        accA.w = fmaf(h.w, w, accA.w);
        if (sl == k) woA = w;
    }
    __builtin_nontemporal_store(accA, &((f32x4*)out_aflow)[nA * 16 + sl]);

    // --- vertex B ---
    float dB[KN];
    #pragma unroll
    for (int k = 0; k < KN; ++k) {
        const f32x4 h = unpack_bf16x4(gB[k]);
        const f32x4 d = h - lvB;
        float s = d.x * d.x;
        s = fmaf(d.y, d.y, s);
        s = fmaf(d.z, d.z, s);
        s = fmaf(d.w, d.w, s);
        s = row16_reduce_add(s);
        dB[k] = ((vB >> k) & 1) ? sqrtf(s) : 0.0f;
    }
    float sumB = 0.0f;
    #pragma unroll
    for (int k = 0; k < KN; ++k) sumB += dB[k];
    const float invB = __builtin_amdgcn_rcpf(sumB);

    f32x4 accB = *(const f32x4*)&bias[sl * 4];
    float woB = 0.0f;
    #pragma unroll
    for (int k = 0; k < KN; ++k) {
        const float dn = dB[k] * invB;
        float w = fmaf(-beta, fminf(dn, alpha), ab);
        w = ((vB >> k) & 1) ? w : 0.0f;
        const f32x4 h = unpack_bf16x4(gB[k]);
        accB.x = fmaf(h.x, w, accB.x);
        accB.y = fmaf(h.y, w, accB.y);
        accB.z = fmaf(h.z, w, accB.z);
        accB.w = fmaf(h.w, w, accB.w);
        if (sl == k) woB = w;
    }
    __builtin_nontemporal_store(accB, &((f32x4*)out_aflow)[nB * 16 + sl]);

    // --- small outputs ---
    if (sl < KN) {
        __builtin_nontemporal_store(woA, &out_weights[nA * KN + sl]);
        __builtin_nontemporal_store(woB, &out_weights[nB * KN + sl]);
        __builtin_nontemporal_store((float)idxrA, &out_idx[nA * KN + sl]);
        __builtin_nontemporal_store((float)idxrB, &out_idx[nB * KN + sl]);
    }
}

extern "C" void kernel_launch(void* const* d_in, const int* in_sizes, int n_in,
                              void* d_out, int out_size, void* d_ws, size_t ws_size,
                              hipStream_t stream) {
    const float* lattice_values = (const float*)d_in[0];
    const float* hidden_state   = (const float*)d_in[1];
    const float* bias           = (const float*)d_in[2];
    const float* alpha          = (const float*)d_in[3];
    const float* beta           = (const float*)d_in[4];
    const int*   neighbor_idx   = (const int*)d_in[5];

    float* out = (float*)d_out;
    float* out_aflow   = out;                           // N*F
    float* out_weights = out + (size_t)NV * FDIM;       // N*K
    float* out_idx     = out_weights + (size_t)NV * KN; // N*K

    uint2* tbl = (uint2*)d_ws;                          // 38.4 MB bf16 table
    compress_kernel<<<(NV * FDIM / 4) / 256, 256, 0, stream>>>(hidden_state, tbl);

    const int blocks = NV / 32;  // 32 vertices per 256-thread block
    aflow_kernel<<<blocks, 256, 0, stream>>>(
        lattice_values, tbl, bias, alpha, beta, neighbor_idx,
        out_aflow, out_weights, out_idx);
}